// Round 20
// baseline (113.294 us; speedup 1.0000x reference)
//
#include <hip/hip_runtime.h>

using half8 = __attribute__((ext_vector_type(8))) _Float16;
using f32x4 = __attribute__((ext_vector_type(4))) float;
using u16x4 = __attribute__((ext_vector_type(4))) unsigned short;

#define Lc 4096
#define Ec 64
#define Mc 64
#define BHc 128

// 2*pi/4096
#define TWO_PI_OVER_L 1.5339807878856412e-3f
#define HALF_PI 1.5707963267948966f
#define PI_F    3.14159265358979323846f

// ---------------------------------------------------------------------------
// r20 (on r19 base):
//  - fwd A-synthesis cheapened: sign/cos folded into the sine argument
//    (sin(x+pi/2)=cos x, sin(x+pi)=-sin x) -> one fmaf + __sinf per element.
//  - wgt pre-converted to f16 in fwd prologue -> mix's 256MB L2 wgt stream
//    halves to 128MB.
// mix structure and inv byte-identical to r19.
// ---------------------------------------------------------------------------

#define LOADT(SET, S) do{                                                     \
    const float* g0_ = xp + (size_t)((S) * 64 + 2 * lp) * Ec;                 \
    const float* g1_ = xp + (size_t)((S) * 64 + 2 * lp + 32) * Ec;            \
    ra[SET][0] = *(const float4*)g0_;  rb[SET][0] = *(const float4*)(g0_ + Ec);\
    ra[SET][1] = *(const float4*)g1_;  rb[SET][1] = *(const float4*)(g1_ + Ec);\
}while(0)

#define PACKT(SET, BUF) do{                                                   \
    _Pragma("unroll")                                                         \
    for (int i_ = 0; i_ < 2; ++i_) {                                          \
        const float* pa_ = (const float*)&ra[SET][i_];                        \
        const float* pb_ = (const float*)&rb[SET][i_];                        \
        unsigned int pk_[4];                                                  \
        _Pragma("unroll")                                                     \
        for (int j_ = 0; j_ < 4; ++j_) {                                      \
            unsigned short ua_ = __builtin_bit_cast(unsigned short, (_Float16)pa_[j_]); \
            unsigned short ub_ = __builtin_bit_cast(unsigned short, (_Float16)pb_[j_]); \
            pk_[j_] = ua_ | ((unsigned int)ub_ << 16);                        \
        }                                                                     \
        _Pragma("unroll")                                                     \
        for (int j_ = 0; j_ < 4; ++j_) {                                      \
            int jr_ = (j_ + col4) & 3;                                        \
            int e_  = col4 * 4 + jr_;                                         \
            int byt_ = (e_ * 128 + lp * 4 + i_ * 64) ^ ((e_ & 7) << 4);       \
            *(unsigned int*)((char*)xs[BUF] + byt_) = pk_[jr_];               \
        }                                                                     \
    }                                                                         \
}while(0)

// A-fragments synthesized in-register: row m2a (A0) / m2a+16 (A1), fixed per
// lane; l = chbase + S*64 + ks*32 + kg*8 + i.  val = sin(ph*c + soff2):
// soff2 = pi/2 for cos rows, pi for -sin rows.
#define MFMA_STEP(S, BUF) do{                                                 \
    _Pragma("unroll")                                                         \
    for (int ks_ = 0; ks_ < 2; ++ks_) {                                       \
        int lb0_ = chbase + (S) * 64 + ks_ * 32 + kg * 8;                     \
        half8 A0_, A1_;                                                       \
        _Pragma("unroll")                                                     \
        for (int i_ = 0; i_ < 8; ++i_) {                                      \
            int pha_ = (ka * (lb0_ + i_)) & (Lc - 1);                         \
            int phb_ = (kb * (lb0_ + i_)) & (Lc - 1);                         \
            A0_[i_] = (_Float16)__sinf(fmaf((float)pha_, TWO_PI_OVER_L, soff2)); \
            A1_[i_] = (_Float16)__sinf(fmaf((float)phb_, TWO_PI_OVER_L, soff2)); \
        }                                                                     \
        _Pragma("unroll")                                                     \
        for (int j_ = 0; j_ < 4; ++j_) {                                      \
            int rbyt_ = ((16 * j_ + lo16) * 128 + ks_ * 64 + kg * 16) ^ ((lo16 & 7) << 4); \
            half8 Bv_ = *(const half8*)((const char*)xs[BUF] + rbyt_);        \
            acc[0][j_] = __builtin_amdgcn_mfma_f32_16x16x32_f16(A0_, Bv_, acc[0][j_], 0, 0, 0); \
            acc[1][j_] = __builtin_amdgcn_mfma_f32_16x16x32_f16(A1_, Bv_, acc[1][j_], 0, 0, 0); \
        }                                                                     \
    }                                                                         \
}while(0)

template<int NCH>
__global__ __launch_bounds__(256) void fwd_k(const float* __restrict__ x,
                                             const float* __restrict__ wgt,
                                             const int* __restrict__ idx,
                                             _Float16* __restrict__ UL,
                                             _Float16* __restrict__ wgtH,
                                             _Float16* __restrict__ selP) {
    constexpr int CH = Lc / NCH;
    constexpr int NT = CH / 64;                // 8 at NCH=8 (even)
    __shared__ _Float16 xs[2][64 * 64];        // 2 x 8KB
    int bh = blockIdx.x, ch = blockIdx.y;
    int tid = threadIdx.x;
    int lane = tid & 63, w = tid >> 6;
    int lo16 = lane & 15, kg = lane >> 4;
    int col4 = tid & 15, lp = tid >> 4;        // staging: e4=col4*4, row-pair lp

    // ---- prologue: UL gen + wgt->f16 convert (grid-strided, coalesced) ----
    {
        int bidlin = blockIdx.y * gridDim.x + blockIdx.x;
        int stride = gridDim.x * gridDim.y * 256;
        for (int u = bidlin * 256 + tid; u < Lc * 128; u += stride) {
            int l_ = u >> 7, m2_ = u & 127, m_ = m2_ & 63;
            int k_ = idx[m_];
            int ph_ = (k_ * l_) & (Lc - 1);
            float soff_ = (m2_ >= 64) ? 0.0f : HALF_PI;
            UL[u] = (_Float16)__sinf(fmaf((float)ph_, TWO_PI_OVER_L, soff_));
        }
        for (int u = bidlin * 256 + tid; u < Ec * Ec * Mc * 2; u += stride)
            wgtH[u] = (_Float16)wgt[u];
    }

    // ---- per-lane A-row constants ----
    int m2a = w * 32 + lo16;                   // A0 row (A1 row = m2a+16)
    int ka = idx[m2a & 63];
    int kb = idx[(m2a + 16) & 63];
    float soff2 = (w >= 2) ? PI_F : HALF_PI;   // -sin rows : cos rows
    int chbase = ch * CH;

    const float* xp = x + ((size_t)bh * Lc + (size_t)ch * CH) * Ec + col4 * 4;

    float4 ra[2][2], rb[2][2];                 // [regset][i]
    LOADT(0, 0);                               // tile 0 -> set0
    LOADT(1, 1);                               // tile 1 -> set1
    PACKT(0, 0);                               // tile 0 -> buf0
    __syncthreads();

    f32x4 acc[2][4] = {};
    for (int t = 0; t < NT / 2; ++t) {
        int s0 = 2 * t, s1 = 2 * t + 1;
        if (s0 + 2 < NT) LOADT(0, s0 + 2);
        PACKT(1, 1);
        MFMA_STEP(s0, 0);
        __syncthreads();
        if (s1 + 2 < NT) LOADT(1, s1 + 2);
        if (s1 + 1 < NT) PACKT(0, 0);
        MFMA_STEP(s1, 1);
        __syncthreads();
    }

    _Float16* op = selP + (size_t)(ch * BHc + bh) * (128 * Ec);
    #pragma unroll
    for (int a = 0; a < 2; ++a)
        #pragma unroll
        for (int j = 0; j < 4; ++j)
            #pragma unroll
            for (int r = 0; r < 4; ++r) {
                int m2 = w * 32 + a * 16 + kg * 4 + r;
                int e  = 16 * j + lo16;
                op[m2 * Ec + e] = (_Float16)acc[a][j][r];
            }
}

// ---------------------------------------------------------------------------
// Mix v2-merged (r16 structure): selP staged/read once per (bh,mh).
// grid (BHc, 2 mh), 512 thr. Thread owns 2 o x 2 m.
// r20: wgt read as f16 (wgtH) -> dominant L2 stream halves.
// Vt[bh][o=64][m2=128] f16: cols 0..63 = s*Re, 64..127 = -s*Im.
// ---------------------------------------------------------------------------
__global__ __launch_bounds__(512) void mix_k(const _Float16* __restrict__ selP,
                                             const _Float16* __restrict__ wgtH,
                                             const int* __restrict__ idx,
                                             _Float16* __restrict__ Vt, int nch) {
    __shared__ float sel_s[64 * 65];           // rows 0..31 Re, 32..63 Im; 16.6KB
    int bh = blockIdx.x, mh = blockIdx.y;      // mh 0..1
    int tid = threadIdx.x;
    #pragma unroll
    for (int i = 0; i < 2; ++i) {
        int f4 = i * 512 + tid;                // 1024 chunks of 4 halfs
        int lr = f4 >> 4, e4 = (f4 & 15) * 4;
        int m2 = (lr < 32) ? (mh * 32 + lr) : (64 + mh * 32 + (lr - 32));
        float ax = 0.f, ay = 0.f, az = 0.f, aw = 0.f;
        for (int chn = 0; chn < nch; ++chn) {
            u16x4 v = *(const u16x4*)(selP + (size_t)(chn * BHc + bh) * 8192
                                           + (size_t)m2 * Ec + e4);
            ax += (float)__builtin_bit_cast(_Float16, (unsigned short)v[0]);
            ay += (float)__builtin_bit_cast(_Float16, (unsigned short)v[1]);
            az += (float)__builtin_bit_cast(_Float16, (unsigned short)v[2]);
            aw += (float)__builtin_bit_cast(_Float16, (unsigned short)v[3]);
        }
        float* dst = &sel_s[lr * 65 + e4];
        dst[0] = ax; dst[1] = ay; dst[2] = az; dst[3] = aw;
    }
    __syncthreads();
    int og = tid & 31, mg = tid >> 5;
    int o0 = og * 2;                           // 2 o per thread (covers all 64)
    int m0 = mh * 32 + mg * 2;                 // 2 m per thread (global m)
    int lm = mg * 2;                           // local Re row
    float rR[2][2] = {{0}}, rI[2][2] = {{0}};
    #pragma unroll 8
    for (int e = 0; e < Ec; ++e) {
        float sr0 = sel_s[lm * 65 + e];
        float sr1 = sel_s[(lm + 1) * 65 + e];
        float si0 = sel_s[(32 + lm) * 65 + e];
        float si1 = sel_s[(32 + lm + 1) * 65 + e];
        #pragma unroll
        for (int i = 0; i < 2; ++i) {
            u16x4 wv = *(const u16x4*)&wgtH[(((size_t)e * Ec + (o0 + i)) * Mc + m0) * 2];
            float wR0 = (float)__builtin_bit_cast(_Float16, (unsigned short)wv[0]);
            float wI0 = (float)__builtin_bit_cast(_Float16, (unsigned short)wv[1]);
            float wR1 = (float)__builtin_bit_cast(_Float16, (unsigned short)wv[2]);
            float wI1 = (float)__builtin_bit_cast(_Float16, (unsigned short)wv[3]);
            rR[i][0] += sr0 * wR0 - si0 * wI0;
            rI[i][0] += sr0 * wI0 + si0 * wR0;
            rR[i][1] += sr1 * wR1 - si1 * wI1;
            rI[i][1] += sr1 * wI1 + si1 * wR1;
        }
    }
    float s0 = (idx[m0] == 0 ? 1.0f : 2.0f) / (float)Lc;
    float s1 = (idx[m0 + 1] == 0 ? 1.0f : 2.0f) / (float)Lc;
    #pragma unroll
    for (int i = 0; i < 2; ++i) {
        _Float16* vp = Vt + ((size_t)bh * 64 + o0 + i) * 128;
        unsigned short r0 = __builtin_bit_cast(unsigned short, (_Float16)(rR[i][0] * s0));
        unsigned short r1 = __builtin_bit_cast(unsigned short, (_Float16)(rR[i][1] * s1));
        unsigned short i0 = __builtin_bit_cast(unsigned short, (_Float16)(-rI[i][0] * s0));
        unsigned short i1 = __builtin_bit_cast(unsigned short, (_Float16)(-rI[i][1] * s1));
        *(unsigned int*)&vp[m0]      = r0 | ((unsigned int)r1 << 16);
        *(unsigned int*)&vp[64 + m0] = i0 | ((unsigned int)i1 << 16);
    }
}

// ---------------------------------------------------------------------------
// Inverse: out[bh][l][o] = sum_{m2} UL[l][m2] * V[m2][o]   (unchanged)
// grid (BHc, 16), 256 thr. Wave w owns l rows [64w, 64w+64) of a 256-l block.
// Vt staged in LDS [o][136] (17-bank stride).
// ---------------------------------------------------------------------------
__global__ __launch_bounds__(256) void inv_k(const _Float16* __restrict__ UL,
                                             const _Float16* __restrict__ Vt,
                                             float* __restrict__ out) {
    __shared__ _Float16 vs[64 * 136];          // 17.4KB
    int bh = blockIdx.x, lb = blockIdx.y;
    int tid = threadIdx.x, lane = tid & 63, w = tid >> 6;
    int lo16 = lane & 15, kg = lane >> 4;
    #pragma unroll
    for (int i = 0; i < 4; ++i) {
        int f = i * 256 + tid;                 // 1024 chunks of 8 f16
        int row = f >> 4, seg = f & 15;
        uint4 t4 = *(const uint4*)(Vt + (size_t)bh * 8192 + row * 128 + seg * 8);
        *(uint4*)&vs[row * 136 + seg * 8] = t4;
    }
    __syncthreads();
    int lt0 = lb * 256 + w * 64;
    const _Float16* up = UL + (size_t)(lt0 + lo16) * 128 + kg * 8;
    f32x4 acc[4][4] = {};
    #pragma unroll
    for (int ks = 0; ks < 4; ++ks) {
        half8 Af[4];
        #pragma unroll
        for (int a = 0; a < 4; ++a)
            Af[a] = *(const half8*)(up + (size_t)a * 16 * 128 + ks * 32);
        #pragma unroll
        for (int j = 0; j < 4; ++j) {
            half8 Bf = *(const half8*)&vs[(16 * j + lo16) * 136 + ks * 32 + kg * 8];
            #pragma unroll
            for (int a = 0; a < 4; ++a)
                acc[a][j] = __builtin_amdgcn_mfma_f32_16x16x32_f16(Af[a], Bf, acc[a][j], 0, 0, 0);
        }
    }
    float* op = out + ((size_t)bh * Lc + lt0) * Ec;
    #pragma unroll
    for (int a = 0; a < 4; ++a)
        #pragma unroll
        for (int j = 0; j < 4; ++j)
            #pragma unroll
            for (int r = 0; r < 4; ++r) {
                int ll = a * 16 + kg * 4 + r;
                int o  = 16 * j + lo16;
                op[(size_t)ll * Ec + o] = acc[a][j][r];
            }
}

// ---------------------------------------------------------------------------
extern "C" void kernel_launch(void* const* d_in, const int* in_sizes, int n_in,
                              void* d_out, int out_size, void* d_ws, size_t ws_size,
                              hipStream_t stream) {
    const float* x   = (const float*)d_in[0];
    const float* wgt = (const float*)d_in[1];
    const int*   idx = (const int*)d_in[2];
    float* out = (float*)d_out;

    // ws layout: selP f16 (nch*2MB) | UL (1MB) | Vt (2MB) | wgtH (1MB)
    size_t tail  = ((size_t)Lc * 128 + (size_t)BHc * 8192 + (size_t)Ec * Ec * Mc * 2) * 2;
    size_t need8 = (size_t)8 * BHc * 8192 * 2 + tail;
    int nch = (ws_size >= need8) ? 8 : 4;

    char* ws = (char*)d_ws;
    _Float16* selP = (_Float16*)ws;
    _Float16* UL   = (_Float16*)(ws + (size_t)nch * BHc * 8192 * 2);
    _Float16* Vt   = UL + (size_t)Lc * 128;
    _Float16* wgtH = Vt + (size_t)BHc * 8192;

    if (nch == 8)
        fwd_k<8><<<dim3(BHc, 8), 256, 0, stream>>>(x, wgt, idx, UL, wgtH, selP);
    else
        fwd_k<4><<<dim3(BHc, 4), 256, 0, stream>>>(x, wgt, idx, UL, wgtH, selP);
    mix_k<<<dim3(BHc, 2), 512, 0, stream>>>(selP, wgtH, idx, Vt, nch);
    inv_k<<<dim3(BHc, 16), 256, 0, stream>>>(UL, Vt, out);
}

// Round 21
// 110.418 us; speedup vs baseline: 1.0260x; 1.0260x over previous
//
#include <hip/hip_runtime.h>

using half8 = __attribute__((ext_vector_type(8))) _Float16;
using f32x4 = __attribute__((ext_vector_type(4))) float;
using u16x4 = __attribute__((ext_vector_type(4))) unsigned short;

#define Lc 4096
#define Ec 64
#define Mc 64
#define BHc 128

// 2*pi/4096
#define TWO_PI_OVER_L 1.5339807878856412e-3f
#define HALF_PI 1.5707963267948966f

// ---------------------------------------------------------------------------
// r21 = r19 verbatim (best-known, 110.9 us). r20's bundle (fmaf-sin fold +
// wgt f16) regressed and is reverted: wgt is only 2MB (L2-resident), so the
// f16 conversion saved no real traffic while halving mix's load width.
//
// Structure: 3 kernels.
//  fwd: twid-free — A-fragments synthesized in-register (fixed k per lane,
//       32 __sinf/tile), UL generated in prologue; r8 dbuf pipeline.
//  mix: r16 merged 512-thr, selP staged once per (bh,mh).
//  inv: r10 LDS-staged Vt, direct coalesced stores.
// ---------------------------------------------------------------------------

#define LOADT(SET, S) do{                                                     \
    const float* g0_ = xp + (size_t)((S) * 64 + 2 * lp) * Ec;                 \
    const float* g1_ = xp + (size_t)((S) * 64 + 2 * lp + 32) * Ec;            \
    ra[SET][0] = *(const float4*)g0_;  rb[SET][0] = *(const float4*)(g0_ + Ec);\
    ra[SET][1] = *(const float4*)g1_;  rb[SET][1] = *(const float4*)(g1_ + Ec);\
}while(0)

#define PACKT(SET, BUF) do{                                                   \
    _Pragma("unroll")                                                         \
    for (int i_ = 0; i_ < 2; ++i_) {                                          \
        const float* pa_ = (const float*)&ra[SET][i_];                        \
        const float* pb_ = (const float*)&rb[SET][i_];                        \
        unsigned int pk_[4];                                                  \
        _Pragma("unroll")                                                     \
        for (int j_ = 0; j_ < 4; ++j_) {                                      \
            unsigned short ua_ = __builtin_bit_cast(unsigned short, (_Float16)pa_[j_]); \
            unsigned short ub_ = __builtin_bit_cast(unsigned short, (_Float16)pb_[j_]); \
            pk_[j_] = ua_ | ((unsigned int)ub_ << 16);                        \
        }                                                                     \
        _Pragma("unroll")                                                     \
        for (int j_ = 0; j_ < 4; ++j_) {                                      \
            int jr_ = (j_ + col4) & 3;                                        \
            int e_  = col4 * 4 + jr_;                                         \
            int byt_ = (e_ * 128 + lp * 4 + i_ * 64) ^ ((e_ & 7) << 4);       \
            *(unsigned int*)((char*)xs[BUF] + byt_) = pk_[jr_];               \
        }                                                                     \
    }                                                                         \
}while(0)

// A-fragments synthesized in-register: row m2a (A0) / m2b=m2a+16 (A1), fixed
// per lane; l = chbase + S*64 + ks*32 + kg*8 + i.  val = ssgn*sin(ang+soff).
#define MFMA_STEP(S, BUF) do{                                                 \
    _Pragma("unroll")                                                         \
    for (int ks_ = 0; ks_ < 2; ++ks_) {                                       \
        int lb0_ = chbase + (S) * 64 + ks_ * 32 + kg * 8;                     \
        half8 A0_, A1_;                                                       \
        _Pragma("unroll")                                                     \
        for (int i_ = 0; i_ < 8; ++i_) {                                      \
            int pha_ = (ka * (lb0_ + i_)) & (Lc - 1);                         \
            int phb_ = (kb * (lb0_ + i_)) & (Lc - 1);                         \
            float va_ = ssgn * __sinf((float)pha_ * TWO_PI_OVER_L + soff);    \
            float vb_ = ssgn * __sinf((float)phb_ * TWO_PI_OVER_L + soff);    \
            A0_[i_] = (_Float16)va_;                                          \
            A1_[i_] = (_Float16)vb_;                                          \
        }                                                                     \
        _Pragma("unroll")                                                     \
        for (int j_ = 0; j_ < 4; ++j_) {                                      \
            int rbyt_ = ((16 * j_ + lo16) * 128 + ks_ * 64 + kg * 16) ^ ((lo16 & 7) << 4); \
            half8 Bv_ = *(const half8*)((const char*)xs[BUF] + rbyt_);        \
            acc[0][j_] = __builtin_amdgcn_mfma_f32_16x16x32_f16(A0_, Bv_, acc[0][j_], 0, 0, 0); \
            acc[1][j_] = __builtin_amdgcn_mfma_f32_16x16x32_f16(A1_, Bv_, acc[1][j_], 0, 0, 0); \
        }                                                                     \
    }                                                                         \
}while(0)

template<int NCH>
__global__ __launch_bounds__(256) void fwd_k(const float* __restrict__ x,
                                             const int* __restrict__ idx,
                                             _Float16* __restrict__ UL,
                                             _Float16* __restrict__ selP) {
    constexpr int CH = Lc / NCH;
    constexpr int NT = CH / 64;                // 8 at NCH=8 (even)
    __shared__ _Float16 xs[2][64 * 64];        // 2 x 8KB
    int bh = blockIdx.x, ch = blockIdx.y;
    int tid = threadIdx.x;
    int lane = tid & 63, w = tid >> 6;
    int lo16 = lane & 15, kg = lane >> 4;
    int col4 = tid & 15, lp = tid >> 4;        // staging: e4=col4*4, row-pair lp

    // ---- UL generation prologue (grid-strided, coalesced in m2) ----
    {
        int bidlin = blockIdx.y * gridDim.x + blockIdx.x;
        int stride = gridDim.x * gridDim.y * 256;
        for (int u = bidlin * 256 + tid; u < Lc * 128; u += stride) {
            int l_ = u >> 7, m2_ = u & 127, m_ = m2_ & 63;
            int k_ = idx[m_];
            int ph_ = (k_ * l_) & (Lc - 1);
            float ang_ = (float)ph_ * TWO_PI_OVER_L;
            UL[u] = (_Float16)((m2_ >= 64) ? __sinf(ang_) : __cosf(ang_));
        }
    }

    // ---- per-lane A-row constants ----
    int m2a = w * 32 + lo16;                   // A0 row (A1 row = m2a+16)
    int ka = idx[m2a & 63];
    int kb = idx[(m2a + 16) & 63];
    bool neg = (w >= 2);                       // rows >=64 are -sin rows
    float ssgn = neg ? -1.0f : 1.0f;
    float soff = neg ? 0.0f : HALF_PI;         // cos(x) = sin(x + pi/2)
    int chbase = ch * CH;

    const float* xp = x + ((size_t)bh * Lc + (size_t)ch * CH) * Ec + col4 * 4;

    float4 ra[2][2], rb[2][2];                 // [regset][i]
    LOADT(0, 0);                               // tile 0 -> set0
    LOADT(1, 1);                               // tile 1 -> set1
    PACKT(0, 0);                               // tile 0 -> buf0
    __syncthreads();

    f32x4 acc[2][4] = {};
    for (int t = 0; t < NT / 2; ++t) {
        int s0 = 2 * t, s1 = 2 * t + 1;
        if (s0 + 2 < NT) LOADT(0, s0 + 2);
        PACKT(1, 1);
        MFMA_STEP(s0, 0);
        __syncthreads();
        if (s1 + 2 < NT) LOADT(1, s1 + 2);
        if (s1 + 1 < NT) PACKT(0, 0);
        MFMA_STEP(s1, 1);
        __syncthreads();
    }

    _Float16* op = selP + (size_t)(ch * BHc + bh) * (128 * Ec);
    #pragma unroll
    for (int a = 0; a < 2; ++a)
        #pragma unroll
        for (int j = 0; j < 4; ++j)
            #pragma unroll
            for (int r = 0; r < 4; ++r) {
                int m2 = w * 32 + a * 16 + kg * 4 + r;
                int e  = 16 * j + lo16;
                op[m2 * Ec + e] = (_Float16)acc[a][j][r];
            }
}

// ---------------------------------------------------------------------------
// Mix v2-merged (r16, unchanged): selP staged/read once per (bh,mh).
// grid (BHc, 2 mh), 512 thr. Thread owns 2 o x 2 m.
// Vt[bh][o=64][m2=128] f16: cols 0..63 = s*Re, 64..127 = -s*Im.
// ---------------------------------------------------------------------------
__global__ __launch_bounds__(512) void mix_k(const _Float16* __restrict__ selP,
                                             const float* __restrict__ wgt,
                                             const int* __restrict__ idx,
                                             _Float16* __restrict__ Vt, int nch) {
    __shared__ float sel_s[64 * 65];           // rows 0..31 Re, 32..63 Im; 16.6KB
    int bh = blockIdx.x, mh = blockIdx.y;      // mh 0..1
    int tid = threadIdx.x;
    #pragma unroll
    for (int i = 0; i < 2; ++i) {
        int f4 = i * 512 + tid;                // 1024 chunks of 4 halfs
        int lr = f4 >> 4, e4 = (f4 & 15) * 4;
        int m2 = (lr < 32) ? (mh * 32 + lr) : (64 + mh * 32 + (lr - 32));
        float ax = 0.f, ay = 0.f, az = 0.f, aw = 0.f;
        for (int chn = 0; chn < nch; ++chn) {
            u16x4 v = *(const u16x4*)(selP + (size_t)(chn * BHc + bh) * 8192
                                           + (size_t)m2 * Ec + e4);
            ax += (float)__builtin_bit_cast(_Float16, (unsigned short)v[0]);
            ay += (float)__builtin_bit_cast(_Float16, (unsigned short)v[1]);
            az += (float)__builtin_bit_cast(_Float16, (unsigned short)v[2]);
            aw += (float)__builtin_bit_cast(_Float16, (unsigned short)v[3]);
        }
        float* dst = &sel_s[lr * 65 + e4];
        dst[0] = ax; dst[1] = ay; dst[2] = az; dst[3] = aw;
    }
    __syncthreads();
    int og = tid & 31, mg = tid >> 5;
    int o0 = og * 2;                           // 2 o per thread (covers all 64)
    int m0 = mh * 32 + mg * 2;                 // 2 m per thread (global m)
    int lm = mg * 2;                           // local Re row
    float rR[2][2] = {{0}}, rI[2][2] = {{0}};
    #pragma unroll 8
    for (int e = 0; e < Ec; ++e) {
        float sr0 = sel_s[lm * 65 + e];
        float sr1 = sel_s[(lm + 1) * 65 + e];
        float si0 = sel_s[(32 + lm) * 65 + e];
        float si1 = sel_s[(32 + lm + 1) * 65 + e];
        #pragma unroll
        for (int i = 0; i < 2; ++i) {
            const float4* wp = (const float4*)&wgt[(((size_t)e * Ec + (o0 + i)) * Mc + m0) * 2];
            float4 wv = *wp;   // wR[m0], wI[m0], wR[m0+1], wI[m0+1]
            rR[i][0] += sr0 * wv.x - si0 * wv.y;
            rI[i][0] += sr0 * wv.y + si0 * wv.x;
            rR[i][1] += sr1 * wv.z - si1 * wv.w;
            rI[i][1] += sr1 * wv.w + si1 * wv.z;
        }
    }
    float s0 = (idx[m0] == 0 ? 1.0f : 2.0f) / (float)Lc;
    float s1 = (idx[m0 + 1] == 0 ? 1.0f : 2.0f) / (float)Lc;
    #pragma unroll
    for (int i = 0; i < 2; ++i) {
        _Float16* vp = Vt + ((size_t)bh * 64 + o0 + i) * 128;
        unsigned short r0 = __builtin_bit_cast(unsigned short, (_Float16)(rR[i][0] * s0));
        unsigned short r1 = __builtin_bit_cast(unsigned short, (_Float16)(rR[i][1] * s1));
        unsigned short i0 = __builtin_bit_cast(unsigned short, (_Float16)(-rI[i][0] * s0));
        unsigned short i1 = __builtin_bit_cast(unsigned short, (_Float16)(-rI[i][1] * s1));
        *(unsigned int*)&vp[m0]      = r0 | ((unsigned int)r1 << 16);
        *(unsigned int*)&vp[64 + m0] = i0 | ((unsigned int)i1 << 16);
    }
}

// ---------------------------------------------------------------------------
// Inverse: out[bh][l][o] = sum_{m2} UL[l][m2] * V[m2][o]   (r10/r16 version)
// grid (BHc, 16), 256 thr. Wave w owns l rows [64w, 64w+64) of a 256-l block.
// Vt staged in LDS [o][136] (17-bank stride). UNCHANGED.
// ---------------------------------------------------------------------------
__global__ __launch_bounds__(256) void inv_k(const _Float16* __restrict__ UL,
                                             const _Float16* __restrict__ Vt,
                                             float* __restrict__ out) {
    __shared__ _Float16 vs[64 * 136];          // 17.4KB
    int bh = blockIdx.x, lb = blockIdx.y;
    int tid = threadIdx.x, lane = tid & 63, w = tid >> 6;
    int lo16 = lane & 15, kg = lane >> 4;
    #pragma unroll
    for (int i = 0; i < 4; ++i) {
        int f = i * 256 + tid;                 // 1024 chunks of 8 f16
        int row = f >> 4, seg = f & 15;
        uint4 t4 = *(const uint4*)(Vt + (size_t)bh * 8192 + row * 128 + seg * 8);
        *(uint4*)&vs[row * 136 + seg * 8] = t4;
    }
    __syncthreads();
    int lt0 = lb * 256 + w * 64;
    const _Float16* up = UL + (size_t)(lt0 + lo16) * 128 + kg * 8;
    f32x4 acc[4][4] = {};
    #pragma unroll
    for (int ks = 0; ks < 4; ++ks) {
        half8 Af[4];
        #pragma unroll
        for (int a = 0; a < 4; ++a)
            Af[a] = *(const half8*)(up + (size_t)a * 16 * 128 + ks * 32);
        #pragma unroll
        for (int j = 0; j < 4; ++j) {
            half8 Bf = *(const half8*)&vs[(16 * j + lo16) * 136 + ks * 32 + kg * 8];
            #pragma unroll
            for (int a = 0; a < 4; ++a)
                acc[a][j] = __builtin_amdgcn_mfma_f32_16x16x32_f16(Af[a], Bf, acc[a][j], 0, 0, 0);
        }
    }
    float* op = out + ((size_t)bh * Lc + lt0) * Ec;
    #pragma unroll
    for (int a = 0; a < 4; ++a)
        #pragma unroll
        for (int j = 0; j < 4; ++j)
            #pragma unroll
            for (int r = 0; r < 4; ++r) {
                int ll = a * 16 + kg * 4 + r;
                int o  = 16 * j + lo16;
                op[(size_t)ll * Ec + o] = acc[a][j][r];
            }
}

// ---------------------------------------------------------------------------
extern "C" void kernel_launch(void* const* d_in, const int* in_sizes, int n_in,
                              void* d_out, int out_size, void* d_ws, size_t ws_size,
                              hipStream_t stream) {
    const float* x   = (const float*)d_in[0];
    const float* wgt = (const float*)d_in[1];
    const int*   idx = (const int*)d_in[2];
    float* out = (float*)d_out;

    // workspace layout: selP f16 (nch*2MB) | UL (1MB) | Vt (2MB)
    size_t tail  = ((size_t)Lc * 128 + (size_t)BHc * 8192) * 2;
    size_t need8 = (size_t)8 * BHc * 8192 * 2 + tail;
    int nch = (ws_size >= need8) ? 8 : 4;

    char* ws = (char*)d_ws;
    _Float16* selP = (_Float16*)ws;
    _Float16* UL   = (_Float16*)(ws + (size_t)nch * BHc * 8192 * 2);
    _Float16* Vt   = UL + (size_t)Lc * 128;

    if (nch == 8)
        fwd_k<8><<<dim3(BHc, 8), 256, 0, stream>>>(x, idx, UL, selP);
    else
        fwd_k<4><<<dim3(BHc, 4), 256, 0, stream>>>(x, idx, UL, selP);
    mix_k<<<dim3(BHc, 2), 512, 0, stream>>>(selP, wgt, idx, Vt, nch);
    inv_k<<<dim3(BHc, 16), 256, 0, stream>>>(UL, Vt, out);
}